// Round 12
// baseline (1692.820 us; speedup 1.0000x reference)
//
#include <hip/hip_runtime.h>
#include <hip/hip_fp16.h>

// Problem constants
#define B_  8192
#define L_  128
#define H_  256
#define A_  32
#define T_  65
#define G3  768   // 3*H
#define BM  32    // batch rows per block

typedef _Float16 f16x8 __attribute__((ext_vector_type(8)));
typedef _Float16 f16x4 __attribute__((ext_vector_type(4)));
typedef float    f32x4 __attribute__((ext_vector_type(4)));

static __device__ __forceinline__ float sigm(float x) { return 1.f / (1.f + __expf(-x)); }
static __device__ __forceinline__ float tanh_f(float x) {
  float e = __expf(2.f * x);
  return (e - 1.f) / (e + 1.f);
}

// h-tile LDS swizzle: element (m, c) of a [32][256] fp16 tile stored at
// byte m*512 + ((2c) ^ ((m&7)<<4)).
static __device__ __forceinline__ uint32_t hoff(int m, uint32_t byte_in_row) {
  return (uint32_t)(m * 512) + (byte_in_row ^ (uint32_t)((m & 7) << 4));
}

// A/B fragment read (16x16x32 f16): lane holds row=row, k = kt*32 + 8*g + [0..8)
static __device__ __forceinline__ f16x8 ldFrag(const _Float16* buf, int row, int g, int kt) {
  return *(const f16x8*)((const char*)buf + hoff(row, (uint32_t)(kt * 64 + g * 16)));
}
static __device__ __forceinline__ void stH(_Float16* buf, int m, int c, float v) {
  *(_Float16*)((char*)buf + hoff(m, 2u * (uint32_t)c)) = (_Float16)v;
}
static __device__ __forceinline__ float ldH(const _Float16* buf, int m, int c) {
  return (float)*(const _Float16*)((const char*)buf + hoff(m, 2u * (uint32_t)c));
}

// ---------------- prep kernels (identical to R10 passing version) ----------------

__global__ void prep_convert(const float* __restrict__ latent, const float* __restrict__ Whh,
                             _Float16* __restrict__ latent16, _Float16* __restrict__ Whh16) {
  const int tid = blockIdx.x * blockDim.x + threadIdx.x;
  const int stride = gridDim.x * blockDim.x;
  for (int i = tid; i < B_ * L_; i += stride) latent16[i] = (_Float16)latent[i];
  for (int i = tid; i < G3 * H_; i += stride) Whh16[i] = (_Float16)Whh[i];
}

__global__ void prep_transpose(const float* __restrict__ Wd0, const float* __restrict__ Wd1,
                               const float* __restrict__ Wd2, const float* __restrict__ Wp1,
                               const float* __restrict__ Wp2,
                               _Float16* __restrict__ Wd0T, _Float16* __restrict__ Wd1T,
                               _Float16* __restrict__ Wd2T, _Float16* __restrict__ Wp1T,
                               _Float16* __restrict__ Wp2T) {
  const int tid = blockIdx.x * blockDim.x + threadIdx.x;
  const int stride = gridDim.x * blockDim.x;
  for (int i = tid; i < 256 * 128; i += stride) { int n = i / 128, k = i % 128; Wd0T[i] = (_Float16)Wd0[k * 256 + n]; }
  for (int i = tid; i < 256 * 256; i += stride) { int n = i / 256, k = i % 256; Wd1T[i] = (_Float16)Wd1[k * 256 + n]; }
  for (int i = tid; i < 256 * 256; i += stride) { int n = i / 256, k = i % 256; Wd2T[i] = (_Float16)Wd2[k * 256 + n]; }
  for (int i = tid; i < 32 * 256;  i += stride) { int n = i / 256, k = i % 256; Wp1T[i] = (_Float16)Wp1[k * 32 + n]; }
  for (int i = tid; i < 32 * 32;   i += stride) { int n = i / 32,  k = i % 32;  Wp2T[i] = (_Float16)Wp2[k * 32 + n]; }
}

// Packed gate table: G4[a][c][j] (f16), j=0: r (b_ih+b_hh folded), j=1: z
// (b_ih+b_hh folded), j=2: n (b_ih only), j=3: pad.  One 8B load per cell.
__global__ void prep_g4(const float* __restrict__ embed, const float* __restrict__ W_ih,
                        const float* __restrict__ b_ih, const float* __restrict__ b_hh,
                        _Float16* __restrict__ G4) {
  const int idx = blockIdx.x * blockDim.x + threadIdx.x;   // a*1024 + c*4 + j
  if (idx >= A_ * 256 * 4) return;
  const int j = idx & 3, c = (idx >> 2) & 255, a = idx >> 10;
  if (j == 3) { G4[idx] = (_Float16)0.f; return; }
  const int cc = j * 256 + c;
  float s = b_ih[cc] + (j < 2 ? b_hh[cc] : 0.f);
#pragma unroll
  for (int e = 0; e < 8; ++e) s += embed[a * 8 + e] * W_ih[cc * 8 + e];
  G4[idx] = (_Float16)s;
}

// ---------------- main fused decoder kernel ----------------
// grid = 256 (1 block/CU), block = 512 threads = 8 waves, 2 waves/SIMD at
// 256 regs/wave (amdgpu_waves_per_eu(2,2) pins the allocator target).
// Wave w owns cols c = w*32 + q*16 + lo (q<2).  r,z gate weights register-
// resident (wrz[4][8] = 128 regs); n-gate streamed per phase from the
// L2-resident slice, issue hidden under the r/z MFMAs.  All elementwise
// inputs (gv gathers, hold) prefetched at phase top so VALU runs from regs.

__global__ __launch_bounds__(512)
__attribute__((amdgpu_waves_per_eu(2, 2)))
void decoder_main(
    const _Float16* __restrict__ latent16, const int* __restrict__ target,
    const _Float16* __restrict__ Whh16, const _Float16* __restrict__ G4,
    const _Float16* __restrict__ Wd0T, const _Float16* __restrict__ Wd1T,
    const _Float16* __restrict__ Wd2T, const _Float16* __restrict__ Wp1T,
    const _Float16* __restrict__ Wp2T,
    const float* __restrict__ bd0, const float* __restrict__ bd1, const float* __restrict__ bd2,
    const float* __restrict__ b_hh, const float* __restrict__ bp1, const float* __restrict__ bp2,
    float* __restrict__ out) {
  __shared__ _Float16 hbuf[2][BM * 256];   // 32 KB, swizzled
  __shared__ int      tok_lds[BM * T_];    // 8.3 KB
  __shared__ _Float16 o1_lds[BM * 40];     // 2.5 KB

  const int tid = threadIdx.x;
  const int w  = tid >> 6;       // wave 0..7
  const int l  = tid & 63;
  const int lo = l & 15;
  const int g  = l >> 4;
  const int b0 = blockIdx.x * BM;

  for (int i = tid; i < BM * T_; i += 512) {
    const int m = i / T_, t = i % T_;
    tok_lds[i] = (t == 0) ? 0 : target[(size_t)(b0 + m) * T_ + (t - 1)];
  }

  // ---------- MLP: h0 = relu(relu(latent@Wd0+bd0)@Wd1+bd1)@Wd2+bd2 ----------
  { // GEMM1 (K=128) -> hbuf[0]
    f16x8 af[2][4];
#pragma unroll
    for (int mt = 0; mt < 2; ++mt)
#pragma unroll
      for (int kt = 0; kt < 4; ++kt)
        af[mt][kt] = *(const f16x8*)(latent16 + (size_t)(b0 + mt * 16 + lo) * 128 + kt * 32 + g * 8);
    f32x4 acc[2][2] = {};
#pragma unroll
    for (int q = 0; q < 2; ++q) {
      const _Float16* bb = Wd0T + (size_t)(w * 32 + q * 16 + lo) * 128 + g * 8;
#pragma unroll
      for (int kt = 0; kt < 4; ++kt) {
        f16x8 bf = *(const f16x8*)(bb + kt * 32);
        acc[0][q] = __builtin_amdgcn_mfma_f32_16x16x32_f16(af[0][kt], bf, acc[0][q], 0, 0, 0);
        acc[1][q] = __builtin_amdgcn_mfma_f32_16x16x32_f16(af[1][kt], bf, acc[1][q], 0, 0, 0);
      }
    }
#pragma unroll
    for (int q = 0; q < 2; ++q) {
      const int n = w * 32 + q * 16 + lo;
      const float bv = bd0[n];
#pragma unroll
      for (int mt = 0; mt < 2; ++mt)
#pragma unroll
        for (int i = 0; i < 4; ++i)
          stH(hbuf[0], mt * 16 + 4 * g + i, n, fmaxf(acc[mt][q][i] + bv, 0.f));
    }
  }
  __syncthreads();
  { // GEMM2 (K=256) hbuf[0] -> hbuf[1]
    f16x8 af[2][8];
#pragma unroll
    for (int mt = 0; mt < 2; ++mt)
#pragma unroll
      for (int kt = 0; kt < 8; ++kt) af[mt][kt] = ldFrag(hbuf[0], mt * 16 + lo, g, kt);
    f32x4 acc[2][2] = {};
#pragma unroll
    for (int q = 0; q < 2; ++q) {
      const _Float16* bb = Wd1T + (size_t)(w * 32 + q * 16 + lo) * 256 + g * 8;
#pragma unroll
      for (int kt = 0; kt < 8; ++kt) {
        f16x8 bf = *(const f16x8*)(bb + kt * 32);
        acc[0][q] = __builtin_amdgcn_mfma_f32_16x16x32_f16(af[0][kt], bf, acc[0][q], 0, 0, 0);
        acc[1][q] = __builtin_amdgcn_mfma_f32_16x16x32_f16(af[1][kt], bf, acc[1][q], 0, 0, 0);
      }
    }
#pragma unroll
    for (int q = 0; q < 2; ++q) {
      const int n = w * 32 + q * 16 + lo;
      const float bv = bd1[n];
#pragma unroll
      for (int mt = 0; mt < 2; ++mt)
#pragma unroll
        for (int i = 0; i < 4; ++i)
          stH(hbuf[1], mt * 16 + 4 * g + i, n, fmaxf(acc[mt][q][i] + bv, 0.f));
    }
  }
  __syncthreads();
  { // GEMM3 (K=256, no relu) hbuf[1] -> hbuf[0] (initial hidden)
    f16x8 af[2][8];
#pragma unroll
    for (int mt = 0; mt < 2; ++mt)
#pragma unroll
      for (int kt = 0; kt < 8; ++kt) af[mt][kt] = ldFrag(hbuf[1], mt * 16 + lo, g, kt);
    f32x4 acc[2][2] = {};
#pragma unroll
    for (int q = 0; q < 2; ++q) {
      const _Float16* bb = Wd2T + (size_t)(w * 32 + q * 16 + lo) * 256 + g * 8;
#pragma unroll
      for (int kt = 0; kt < 8; ++kt) {
        f16x8 bf = *(const f16x8*)(bb + kt * 32);
        acc[0][q] = __builtin_amdgcn_mfma_f32_16x16x32_f16(af[0][kt], bf, acc[0][q], 0, 0, 0);
        acc[1][q] = __builtin_amdgcn_mfma_f32_16x16x32_f16(af[1][kt], bf, acc[1][q], 0, 0, 0);
      }
    }
    __syncthreads();
#pragma unroll
    for (int q = 0; q < 2; ++q) {
      const int n = w * 32 + q * 16 + lo;
      const float bv = bd2[n];
#pragma unroll
      for (int mt = 0; mt < 2; ++mt)
#pragma unroll
        for (int i = 0; i < 4; ++i)
          stH(hbuf[0], mt * 16 + 4 * g + i, n, acc[mt][q][i] + bv);
    }
  }
  __syncthreads();

  // ---- hoist r,z gate weights into registers: wrz[4][8] = 128 regs ----
  f16x8 wrz[4][8];
#pragma unroll
  for (int gt = 0; gt < 2; ++gt)
#pragma unroll
    for (int q = 0; q < 2; ++q)
#pragma unroll
      for (int kt = 0; kt < 8; ++kt)
        wrz[gt * 2 + q][kt] =
            *(const f16x8*)(Whh16 + (size_t)(gt * 256 + w * 32 + q * 16 + lo) * 256 + kt * 32 + g * 8);
  const _Float16* nbase[2];
#pragma unroll
  for (int q = 0; q < 2; ++q)
    nbase[q] = Whh16 + (size_t)(512 + w * 32 + q * 16 + lo) * 256 + g * 8;

  float bhn[2];
#pragma unroll
  for (int q = 0; q < 2; ++q) bhn[q] = b_hh[512 + w * 32 + q * 16 + lo];
  // per-lane G4 column offsets (elements), loop-invariant
  const int goff0 = (w * 32 + lo) * 4;
  const int goff1 = (w * 32 + 16 + lo) * 4;

  const int mtp = w & 1, at = w >> 1;      // proj tile of waves 0..3
  float bp1v = 0.f, bp2v = 0.f;
  f16x8 wp2f = {};
  if (w < 4) {
    bp1v = bp1[at * 16 + lo];
    bp2v = bp2[at * 16 + lo];
    wp2f = *(const f16x8*)(Wp2T + (at * 16 + lo) * 32 + g * 8);
  }

  // ---------- GRU time loop ----------
#pragma unroll 1
  for (int t = 0; t < T_; ++t) {
    const _Float16* hr = hbuf[t & 1];
    _Float16* hw = hbuf[(t & 1) ^ 1];

#pragma unroll
    for (int mt = 0; mt < 2; ++mt) {
      // ---- phase top: issue ALL loads the VALU tail will need ----
      int tk[4];
#pragma unroll
      for (int i = 0; i < 4; ++i) tk[i] = tok_lds[(mt * 16 + 4 * g + i) * T_ + t];

      f16x8 af[8];
#pragma unroll
      for (int kt = 0; kt < 8; ++kt) af[kt] = ldFrag(hr, mt * 16 + lo, g, kt);

      f16x4 gvp[4][2];
#pragma unroll
      for (int i = 0; i < 4; ++i) {
        const _Float16* Grow = G4 + (size_t)tk[i] * 1024;
        gvp[i][0] = *(const f16x4*)(Grow + goff0);
        gvp[i][1] = *(const f16x4*)(Grow + goff1);
      }
      float hold[4][2];
#pragma unroll
      for (int i = 0; i < 4; ++i) {
        const int m = mt * 16 + 4 * g + i;
        hold[i][0] = ldH(hr, m, w * 32 + lo);
        hold[i][1] = ldH(hr, m, w * 32 + 16 + lo);
      }
      f16x8 bfn[8];
#pragma unroll
      for (int kt = 0; kt < 8; ++kt) bfn[kt] = *(const f16x8*)(nbase[0] + kt * 32);

      // ---- r,z MFMAs from registers (covers gv/bfn latency) ----
      f32x4 acc[3][2];
#pragma unroll
      for (int gt = 0; gt < 3; ++gt)
#pragma unroll
        for (int q = 0; q < 2; ++q) acc[gt][q] = (f32x4){0.f, 0.f, 0.f, 0.f};
#pragma unroll
      for (int gt = 0; gt < 2; ++gt)
#pragma unroll
        for (int q = 0; q < 2; ++q)
#pragma unroll
          for (int kt = 0; kt < 8; ++kt)
            acc[gt][q] = __builtin_amdgcn_mfma_f32_16x16x32_f16(af[kt], wrz[gt * 2 + q][kt], acc[gt][q], 0, 0, 0);

      // ---- n gate: q=0 from stream, then q=1 ----
#pragma unroll
      for (int kt = 0; kt < 8; ++kt)
        acc[2][0] = __builtin_amdgcn_mfma_f32_16x16x32_f16(af[kt], bfn[kt], acc[2][0], 0, 0, 0);
#pragma unroll
      for (int kt = 0; kt < 8; ++kt) bfn[kt] = *(const f16x8*)(nbase[1] + kt * 32);
#pragma unroll
      for (int kt = 0; kt < 8; ++kt)
        acc[2][1] = __builtin_amdgcn_mfma_f32_16x16x32_f16(af[kt], bfn[kt], acc[2][1], 0, 0, 0);

      // ---- elementwise GRU cell: all inputs already in registers ----
#pragma unroll
      for (int i = 0; i < 4; ++i) {
        const int m = mt * 16 + 4 * g + i;
#pragma unroll
        for (int q = 0; q < 2; ++q) {
          const int c = w * 32 + q * 16 + lo;
          const float r = sigm(acc[0][q][i] + (float)gvp[i][q][0]);
          const float z = sigm(acc[1][q][i] + (float)gvp[i][q][1]);
          const float nn = tanh_f((float)gvp[i][q][2] + r * (acc[2][q][i] + bhn[q]));
          stH(hw, m, c, nn + z * (hold[i][q] - nn));
        }
      }
    }

    // pre-issue proj1 B operands before the barrier (loop-invariant addresses)
    f16x8 b1f[8];
    if (w < 4) {
#pragma unroll
      for (int kt = 0; kt < 8; ++kt)
        b1f[kt] = *(const f16x8*)(Wp1T + (size_t)(at * 16 + lo) * 256 + kt * 32 + g * 8);
    }
    __syncthreads();   // h_{t+1} visible

    // ---- fused projection (2-barrier, waves 0..3, tiles (mtp, at)) ----
    if (w < 4) {
      f32x4 accp = {};
#pragma unroll
      for (int kt = 0; kt < 8; ++kt) {
        f16x8 a1 = ldFrag(hw, mtp * 16 + lo, g, kt);
        accp = __builtin_amdgcn_mfma_f32_16x16x32_f16(a1, b1f[kt], accp, 0, 0, 0);
      }
      const int ac = at * 16 + lo;
#pragma unroll
      for (int i = 0; i < 4; ++i)
        o1_lds[(mtp * 16 + 4 * g + i) * 40 + ac] = (_Float16)fmaxf(accp[i] + bp1v, 0.f);
    }
    __syncthreads();   // o1 complete
    if (w < 4) {
      f16x8 a2 = *(const f16x8*)(o1_lds + (mtp * 16 + lo) * 40 + g * 8);
      f32x4 accl = {};
      accl = __builtin_amdgcn_mfma_f32_16x16x32_f16(a2, wp2f, accl, 0, 0, 0);
#pragma unroll
      for (int i = 0; i < 4; ++i) {
        const int m = mtp * 16 + 4 * g + i;
        out[((size_t)(b0 + m) * T_ + t) * A_ + at * 16 + lo] = accl[i] + bp2v;
      }
    }
    // no 3rd barrier: next o1 write happens after next step's first barrier
  }
}

// ---------------- launch ----------------

extern "C" void kernel_launch(void* const* d_in, const int* in_sizes, int n_in,
                              void* d_out, int out_size, void* d_ws, size_t ws_size,
                              hipStream_t stream) {
  const float* latent = (const float*)d_in[0];
  const int*   target = (const int*)d_in[1];
  const float* embed  = (const float*)d_in[2];
  const float* W_ih   = (const float*)d_in[3];
  const float* b_ih   = (const float*)d_in[4];
  const float* W_hh   = (const float*)d_in[5];
  const float* b_hh   = (const float*)d_in[6];
  const float* Wd0    = (const float*)d_in[7];
  const float* bd0    = (const float*)d_in[8];
  const float* Wd1    = (const float*)d_in[9];
  const float* bd1    = (const float*)d_in[10];
  const float* Wd2    = (const float*)d_in[11];
  const float* bd2    = (const float*)d_in[12];
  const float* Wp1    = (const float*)d_in[13];
  const float* bp1    = (const float*)d_in[14];
  const float* Wp2    = (const float*)d_in[15];
  const float* bp2    = (const float*)d_in[16];
  float* out = (float*)d_out;

  char* ws = (char*)d_ws;
  size_t off = 0;
  auto carve = [&](size_t bytes) { char* p = ws + off; off += (bytes + 255) & ~(size_t)255; return p; };
  _Float16* latent16 = (_Float16*)carve((size_t)B_ * L_ * 2);
  _Float16* Whh16    = (_Float16*)carve((size_t)G3 * H_ * 2);
  _Float16* Wd0T     = (_Float16*)carve(256 * 128 * 2);
  _Float16* Wd1T     = (_Float16*)carve(256 * 256 * 2);
  _Float16* Wd2T     = (_Float16*)carve(256 * 256 * 2);
  _Float16* Wp1T     = (_Float16*)carve(32 * 256 * 2);
  _Float16* Wp2T     = (_Float16*)carve(32 * 32 * 2);
  _Float16* G4       = (_Float16*)carve(A_ * 256 * 4 * 2);

  prep_convert<<<1024, 256, 0, stream>>>(latent, W_hh, latent16, Whh16);
  prep_transpose<<<256, 256, 0, stream>>>(Wd0, Wd1, Wd2, Wp1, Wp2, Wd0T, Wd1T, Wd2T, Wp1T, Wp2T);
  prep_g4<<<(A_ * 256 * 4 + 255) / 256, 256, 0, stream>>>(embed, W_ih, b_ih, b_hh, G4);
  decoder_main<<<B_ / BM, 512, 0, stream>>>(latent16, target, Whh16, G4,
                                            Wd0T, Wd1T, Wd2T, Wp1T, Wp2T,
                                            bd0, bd1, bd2, b_hh, bp1, bp2, out);
}

// Round 13
// 831.855 us; speedup vs baseline: 2.0350x; 2.0350x over previous
//
#include <hip/hip_runtime.h>
#include <hip/hip_fp16.h>

// Problem constants
#define B_  8192
#define L_  128
#define H_  256
#define A_  32
#define T_  65
#define BM  16    // batch rows per block (R10 was 32) -> grid 512 = 2 blocks/CU

typedef _Float16 f16x8 __attribute__((ext_vector_type(8)));
typedef _Float16 f16x4 __attribute__((ext_vector_type(4)));
typedef float    f32x4 __attribute__((ext_vector_type(4)));

static __device__ __forceinline__ float sigm(float x) { return 1.f / (1.f + __expf(-x)); }
static __device__ __forceinline__ float tanh_f(float x) {
  float e = __expf(2.f * x);
  return (e - 1.f) / (e + 1.f);
}

// h-tile LDS swizzle: element (m, c) of a [BM][256] fp16 tile stored at
// byte m*512 + ((2c) ^ ((m&7)<<4)).
static __device__ __forceinline__ uint32_t hoff(int m, uint32_t byte_in_row) {
  return (uint32_t)(m * 512) + (byte_in_row ^ (uint32_t)((m & 7) << 4));
}

// A/B fragment read (16x16x32 f16): lane holds row=row, k = kt*32 + 8*g + [0..8)
static __device__ __forceinline__ f16x8 ldFrag(const _Float16* buf, int row, int g, int kt) {
  return *(const f16x8*)((const char*)buf + hoff(row, (uint32_t)(kt * 64 + g * 16)));
}
static __device__ __forceinline__ void stH(_Float16* buf, int m, int c, float v) {
  *(_Float16*)((char*)buf + hoff(m, 2u * (uint32_t)c)) = (_Float16)v;
}
static __device__ __forceinline__ float ldH(const _Float16* buf, int m, int c) {
  return (float)*(const _Float16*)((const char*)buf + hoff(m, 2u * (uint32_t)c));
}

// ---------------- prep kernels (identical to R10 passing version) ----------------

__global__ void prep_convert(const float* __restrict__ latent, const float* __restrict__ Whh,
                             _Float16* __restrict__ latent16, _Float16* __restrict__ Whh16) {
  const int tid = blockIdx.x * blockDim.x + threadIdx.x;
  const int stride = gridDim.x * blockDim.x;
  for (int i = tid; i < B_ * L_; i += stride) latent16[i] = (_Float16)latent[i];
  for (int i = tid; i < 768 * H_; i += stride) Whh16[i] = (_Float16)Whh[i];
}

__global__ void prep_transpose(const float* __restrict__ Wd0, const float* __restrict__ Wd1,
                               const float* __restrict__ Wd2, const float* __restrict__ Wp1,
                               const float* __restrict__ Wp2,
                               _Float16* __restrict__ Wd0T, _Float16* __restrict__ Wd1T,
                               _Float16* __restrict__ Wd2T, _Float16* __restrict__ Wp1T,
                               _Float16* __restrict__ Wp2T) {
  const int tid = blockIdx.x * blockDim.x + threadIdx.x;
  const int stride = gridDim.x * blockDim.x;
  for (int i = tid; i < 256 * 128; i += stride) { int n = i / 128, k = i % 128; Wd0T[i] = (_Float16)Wd0[k * 256 + n]; }
  for (int i = tid; i < 256 * 256; i += stride) { int n = i / 256, k = i % 256; Wd1T[i] = (_Float16)Wd1[k * 256 + n]; }
  for (int i = tid; i < 256 * 256; i += stride) { int n = i / 256, k = i % 256; Wd2T[i] = (_Float16)Wd2[k * 256 + n]; }
  for (int i = tid; i < 32 * 256;  i += stride) { int n = i / 256, k = i % 256; Wp1T[i] = (_Float16)Wp1[k * 32 + n]; }
  for (int i = tid; i < 32 * 32;   i += stride) { int n = i / 32,  k = i % 32;  Wp2T[i] = (_Float16)Wp2[k * 32 + n]; }
}

// Packed gate table: G4[a][c][j] (f16), j=0: r (b_ih+b_hh folded), j=1: z
// (b_ih+b_hh folded), j=2: n (b_ih only), j=3: pad.  One 8B load per cell.
__global__ void prep_g4(const float* __restrict__ embed, const float* __restrict__ W_ih,
                        const float* __restrict__ b_ih, const float* __restrict__ b_hh,
                        _Float16* __restrict__ G4) {
  const int idx = blockIdx.x * blockDim.x + threadIdx.x;   // a*1024 + c*4 + j
  if (idx >= A_ * 256 * 4) return;
  const int j = idx & 3, c = (idx >> 2) & 255, a = idx >> 10;
  if (j == 3) { G4[idx] = (_Float16)0.f; return; }
  const int cc = j * 256 + c;
  float s = b_ih[cc] + (j < 2 ? b_hh[cc] : 0.f);
#pragma unroll
  for (int e = 0; e < 8; ++e) s += embed[a * 8 + e] * W_ih[cc * 8 + e];
  G4[idx] = (_Float16)s;
}

// ---------------- main fused decoder kernel ----------------
// grid = 512 (2 blocks/CU), block = 256 threads = 4 waves.  Wave w holds
// W_hh cols [w*64, w*64+64) of all 3 gates in registers (wr[12][8], ~384
// regs incl. AGPRs -- R10-proven allocation shape).  GRU loop streams NO
// weights.  BM=16: single 16-row tile, so per-step work halves and the two
// co-resident blocks interleave latency.  2-barrier fused projection.

__global__ __launch_bounds__(256, 1) void decoder_main(
    const _Float16* __restrict__ latent16, const int* __restrict__ target,
    const _Float16* __restrict__ Whh16, const _Float16* __restrict__ G4,
    const _Float16* __restrict__ Wd0T, const _Float16* __restrict__ Wd1T,
    const _Float16* __restrict__ Wd2T, const _Float16* __restrict__ Wp1T,
    const _Float16* __restrict__ Wp2T,
    const float* __restrict__ bd0, const float* __restrict__ bd1, const float* __restrict__ bd2,
    const float* __restrict__ b_hh, const float* __restrict__ bp1, const float* __restrict__ bp2,
    float* __restrict__ out) {
  __shared__ _Float16 hbuf[2][BM * 256];   // 16 KB, swizzled
  __shared__ int      tok_lds[BM * T_];    // 4.2 KB
  __shared__ _Float16 o1_lds[BM * 40];     // 1.3 KB

  const int tid = threadIdx.x;
  const int w  = tid >> 6;       // wave 0..3
  const int l  = tid & 63;
  const int lo = l & 15;
  const int g  = l >> 4;
  const int b0 = blockIdx.x * BM;

  for (int i = tid; i < BM * T_; i += 256) {
    const int m = i / T_, t = i % T_;
    tok_lds[i] = (t == 0) ? 0 : target[(size_t)(b0 + m) * T_ + (t - 1)];
  }

  // ---------- MLP: h0 = relu(relu(latent@Wd0+bd0)@Wd1+bd1)@Wd2+bd2 ----------
  { // GEMM1 (K=128) -> hbuf[0]
    f16x8 af[4];
#pragma unroll
    for (int kt = 0; kt < 4; ++kt)
      af[kt] = *(const f16x8*)(latent16 + (size_t)(b0 + lo) * 128 + kt * 32 + g * 8);
    f32x4 acc[4] = {};
#pragma unroll
    for (int q = 0; q < 4; ++q) {
      const _Float16* bb = Wd0T + (size_t)(w * 64 + q * 16 + lo) * 128 + g * 8;
#pragma unroll
      for (int kt = 0; kt < 4; ++kt) {
        f16x8 bf = *(const f16x8*)(bb + kt * 32);
        acc[q] = __builtin_amdgcn_mfma_f32_16x16x32_f16(af[kt], bf, acc[q], 0, 0, 0);
      }
    }
#pragma unroll
    for (int q = 0; q < 4; ++q) {
      const int n = w * 64 + q * 16 + lo;
      const float bv = bd0[n];
#pragma unroll
      for (int i = 0; i < 4; ++i)
        stH(hbuf[0], 4 * g + i, n, fmaxf(acc[q][i] + bv, 0.f));
    }
  }
  __syncthreads();
  { // GEMM2 (K=256) hbuf[0] -> hbuf[1]
    f16x8 af[8];
#pragma unroll
    for (int kt = 0; kt < 8; ++kt) af[kt] = ldFrag(hbuf[0], lo, g, kt);
    f32x4 acc[4] = {};
#pragma unroll
    for (int q = 0; q < 4; ++q) {
      const _Float16* bb = Wd1T + (size_t)(w * 64 + q * 16 + lo) * 256 + g * 8;
#pragma unroll
      for (int kt = 0; kt < 8; ++kt) {
        f16x8 bf = *(const f16x8*)(bb + kt * 32);
        acc[q] = __builtin_amdgcn_mfma_f32_16x16x32_f16(af[kt], bf, acc[q], 0, 0, 0);
      }
    }
#pragma unroll
    for (int q = 0; q < 4; ++q) {
      const int n = w * 64 + q * 16 + lo;
      const float bv = bd1[n];
#pragma unroll
      for (int i = 0; i < 4; ++i)
        stH(hbuf[1], 4 * g + i, n, fmaxf(acc[q][i] + bv, 0.f));
    }
  }
  __syncthreads();
  { // GEMM3 (K=256, no relu) hbuf[1] -> hbuf[0] (initial hidden)
    f16x8 af[8];
#pragma unroll
    for (int kt = 0; kt < 8; ++kt) af[kt] = ldFrag(hbuf[1], lo, g, kt);
    f32x4 acc[4] = {};
#pragma unroll
    for (int q = 0; q < 4; ++q) {
      const _Float16* bb = Wd2T + (size_t)(w * 64 + q * 16 + lo) * 256 + g * 8;
#pragma unroll
      for (int kt = 0; kt < 8; ++kt) {
        f16x8 bf = *(const f16x8*)(bb + kt * 32);
        acc[q] = __builtin_amdgcn_mfma_f32_16x16x32_f16(af[kt], bf, acc[q], 0, 0, 0);
      }
    }
    __syncthreads();
#pragma unroll
    for (int q = 0; q < 4; ++q) {
      const int n = w * 64 + q * 16 + lo;
      const float bv = bd2[n];
#pragma unroll
      for (int i = 0; i < 4; ++i)
        stH(hbuf[0], 4 * g + i, n, acc[q][i] + bv);
    }
  }
  __syncthreads();

  // ---- hoist this wave's full W_hh slice into registers: 12 x 8 = ~384 regs ----
  f16x8 wr[12][8];
#pragma unroll
  for (int gt = 0; gt < 3; ++gt)
#pragma unroll
    for (int q = 0; q < 4; ++q)
#pragma unroll
      for (int kt = 0; kt < 8; ++kt)
        wr[gt * 4 + q][kt] =
            *(const f16x8*)(Whh16 + (size_t)(gt * 256 + w * 64 + q * 16 + lo) * 256 + kt * 32 + g * 8);

  float bhn[4];
#pragma unroll
  for (int q = 0; q < 4; ++q) bhn[q] = b_hh[512 + w * 64 + q * 16 + lo];
  const int at = w;                        // proj tile of waves 0..1 (cols at*16)
  float bp1v = 0.f, bp2v = 0.f;
  if (w < 2) { bp1v = bp1[at * 16 + lo]; bp2v = bp2[at * 16 + lo]; }

  // ---------- GRU time loop: zero weight traffic ----------
#pragma unroll 1
  for (int t = 0; t < T_; ++t) {
    const _Float16* hr = hbuf[t & 1];
    _Float16* hw = hbuf[(t & 1) ^ 1];

    f16x8 af[8];
#pragma unroll
    for (int kt = 0; kt < 8; ++kt) af[kt] = ldFrag(hr, lo, g, kt);

    f32x4 acc[3][4];
#pragma unroll
    for (int gt = 0; gt < 3; ++gt)
#pragma unroll
      for (int q = 0; q < 4; ++q) acc[gt][q] = (f32x4){0.f, 0.f, 0.f, 0.f};
#pragma unroll
    for (int gt = 0; gt < 3; ++gt)
#pragma unroll
      for (int q = 0; q < 4; ++q)
#pragma unroll
        for (int kt = 0; kt < 8; ++kt)
          acc[gt][q] = __builtin_amdgcn_mfma_f32_16x16x32_f16(af[kt], wr[gt * 4 + q][kt], acc[gt][q], 0, 0, 0);

    // elementwise GRU cell for rows m = 4g + i, cols c = w*64 + q*16 + lo
#pragma unroll
    for (int i = 0; i < 4; ++i) {
      const int m = 4 * g + i;
      const int tok = tok_lds[m * T_ + t];
      const _Float16* Grow = G4 + (size_t)tok * 1024;
#pragma unroll
      for (int q = 0; q < 4; ++q) {
        const int c = w * 64 + q * 16 + lo;
        f16x4 gv = *(const f16x4*)(Grow + c * 4);
        const float r = sigm(acc[0][q][i] + (float)gv[0]);
        const float z = sigm(acc[1][q][i] + (float)gv[1]);
        const float nn = tanh_f((float)gv[2] + r * (acc[2][q][i] + bhn[q]));
        const float hold = ldH(hr, m, c);
        stH(hw, m, c, nn + z * (hold - nn));
      }
    }
    __syncthreads();   // h_{t+1} visible

    // ---- fused projection (2-barrier structure, waves 0..1, 2 tiles) ----
    if (w < 2) { // stage-1: o1 = relu(h_new @ Wp1 + bp1), cols at*16..
      f32x4 accp = {};
#pragma unroll
      for (int kt = 0; kt < 8; ++kt) {
        f16x8 a1 = ldFrag(hw, lo, g, kt);
        f16x8 b1 = *(const f16x8*)(Wp1T + (size_t)(at * 16 + lo) * 256 + kt * 32 + g * 8);
        accp = __builtin_amdgcn_mfma_f32_16x16x32_f16(a1, b1, accp, 0, 0, 0);
      }
      const int ac = at * 16 + lo;
#pragma unroll
      for (int i = 0; i < 4; ++i)
        o1_lds[(4 * g + i) * 40 + ac] = (_Float16)fmaxf(accp[i] + bp1v, 0.f);
    }
    __syncthreads();   // o1 complete
    if (w < 2) { // stage-2: out_t = relu-done o1 @ Wp2 + bp2
      f16x8 a2 = *(const f16x8*)(o1_lds + lo * 40 + g * 8);
      f16x8 b2 = *(const f16x8*)(Wp2T + (at * 16 + lo) * 32 + g * 8);
      f32x4 accl = {};
      accl = __builtin_amdgcn_mfma_f32_16x16x32_f16(a2, b2, accl, 0, 0, 0);
#pragma unroll
      for (int i = 0; i < 4; ++i) {
        const int m = 4 * g + i;
        out[((size_t)(b0 + m) * T_ + t) * A_ + at * 16 + lo] = accl[i] + bp2v;
      }
    }
    // no 3rd barrier: next o1 write is after the next step's first barrier
  }
}

// ---------------- launch ----------------

extern "C" void kernel_launch(void* const* d_in, const int* in_sizes, int n_in,
                              void* d_out, int out_size, void* d_ws, size_t ws_size,
                              hipStream_t stream) {
  const float* latent = (const float*)d_in[0];
  const int*   target = (const int*)d_in[1];
  const float* embed  = (const float*)d_in[2];
  const float* W_ih   = (const float*)d_in[3];
  const float* b_ih   = (const float*)d_in[4];
  const float* W_hh   = (const float*)d_in[5];
  const float* b_hh   = (const float*)d_in[6];
  const float* Wd0    = (const float*)d_in[7];
  const float* bd0    = (const float*)d_in[8];
  const float* Wd1    = (const float*)d_in[9];
  const float* bd1    = (const float*)d_in[10];
  const float* Wd2    = (const float*)d_in[11];
  const float* bd2    = (const float*)d_in[12];
  const float* Wp1    = (const float*)d_in[13];
  const float* bp1    = (const float*)d_in[14];
  const float* Wp2    = (const float*)d_in[15];
  const float* bp2    = (const float*)d_in[16];
  float* out = (float*)d_out;

  char* ws = (char*)d_ws;
  size_t off = 0;
  auto carve = [&](size_t bytes) { char* p = ws + off; off += (bytes + 255) & ~(size_t)255; return p; };
  _Float16* latent16 = (_Float16*)carve((size_t)B_ * L_ * 2);
  _Float16* Whh16    = (_Float16*)carve((size_t)768 * H_ * 2);
  _Float16* Wd0T     = (_Float16*)carve(256 * 128 * 2);
  _Float16* Wd1T     = (_Float16*)carve(256 * 256 * 2);
  _Float16* Wd2T     = (_Float16*)carve(256 * 256 * 2);
  _Float16* Wp1T     = (_Float16*)carve(32 * 256 * 2);
  _Float16* Wp2T     = (_Float16*)carve(32 * 32 * 2);
  _Float16* G4       = (_Float16*)carve(A_ * 256 * 4 * 2);

  prep_convert<<<1024, 256, 0, stream>>>(latent, W_hh, latent16, Whh16);
  prep_transpose<<<256, 256, 0, stream>>>(Wd0, Wd1, Wd2, Wp1, Wp2, Wd0T, Wd1T, Wd2T, Wp1T, Wp2T);
  prep_g4<<<(A_ * 256 * 4 + 255) / 256, 256, 0, stream>>>(embed, W_ih, b_ih, b_hh, G4);
  decoder_main<<<B_ / BM, 256, 0, stream>>>(latent16, target, Whh16, G4,
                                            Wd0T, Wd1T, Wd2T, Wp1T, Wp2T,
                                            bd0, bd1, bd2, b_hh, bp1, bp2, out);
}